// Round 1
// baseline (734.580 us; speedup 1.0000x reference)
//
#include <hip/hip_runtime.h>

// ============================================================================
// ps_component round 5: R=4 rows/block, 512-thread blocks.
// Theory: round-4 kernel was LDS-read-BW-bound (af fragments re-read per
// 2 MFMAs). Now each wave owns one 16-col N-slice x all couts x 4 rows:
// af reused 4x (rows), bfv reused MT x (couts) -> reads/MFMA 0.625 -> 0.375,
// LDS cycles/stage (~2624) < MFMA cycles/stage (~3725).
//  - Xs chunk-double-buffered [2][4qg][6 rows][W+2][8]; writes (2 rows/stage)
//    go to the inactive buffer -> still ONE barrier per stage.
//  - Ws stage-double-buffered relay as before (3 s8v/thread at 512 thr).
//  - Global X loads prefetched one stage ahead into VGPRs.
// ============================================================================

typedef short s8v __attribute__((ext_vector_type(8)));   // 8 x bf16 bits
typedef float f4v __attribute__((ext_vector_type(4)));

#define BARRIER() asm volatile("s_waitcnt lgkmcnt(0)\n\ts_barrier" ::: "memory")

__device__ __forceinline__ unsigned short f32_bf16_rne(float f) {
  union { float f; unsigned int u; } v;
  v.f = f;
  unsigned int u = v.u;
  u += 0x7FFFu + ((u >> 16) & 1u);
  return (unsigned short)(u >> 16);
}

// ---------------- prep W: OIHW fp32 -> [s][chunk][kh][kw][qg][cout][8c] -----
__global__ void prep_w_k(const float* __restrict__ w1,
                         const float* __restrict__ w2,
                         const float* __restrict__ w3,
                         unsigned short* __restrict__ out) {
  int idx = blockIdx.x * 256 + threadIdx.x;   // total 3*4*3*3*4*128*8 = 442368
  if (idx >= 442368) return;
  int i    = idx & 7;
  int cout = (idx >> 3) & 127;
  int t    = idx >> 10;
  int qg = t & 3; t >>= 2;
  int kw = t % 3; t /= 3;
  int kh = t % 3; t /= 3;
  int chunk = t & 3; t >>= 2;
  int s = t;
  const float* w = (s == 0) ? w1 : ((s == 1) ? w2 : w3);
  int cin = chunk * 32 + qg * 8 + i;
  out[idx] = f32_bf16_rne(w[((cout * 128 + cin) * 3 + kh) * 3 + kw]);
}

// ---------------- init: out[b,c] = b_t * sum_h w_pl[h] + b_pl ---------------
__global__ void init_out_k(float* __restrict__ out,
                           const float* bt1, const float* bt2,
                           const float* bt3, const float* bt4,
                           const float* wpl1, const float* bpl1,
                           const float* wpl2, const float* bpl2,
                           const float* wpl3, const float* bpl3,
                           const float* wpl4, const float* bpl4) {
  int idx = blockIdx.x * 256 + threadIdx.x;
  if (idx >= 64 * 240) return;
  int c = idx % 240;
  const float* wpl; const float* bpl; const float* bt; int H;
  if (c < 128)      { wpl = wpl1; bpl = bpl1; bt = bt1; H = 64; }
  else if (c < 192) { wpl = wpl2; bpl = bpl2; bt = bt2; H = 32; }
  else if (c < 224) { wpl = wpl3; bpl = bpl3; bt = bt3; H = 16; }
  else              { wpl = wpl4; bpl = bpl4; bt = bt4; H = 8;  }
  float s = 0.f;
  for (int h = 0; h < H; ++h) s += wpl[h];
  out[idx] = bt[0] * s + bpl[0];
}

// ---------------- level 4: pure linear reduction over p5 --------------------
__global__ void level4_k(const float* __restrict__ p5,
                         const float* __restrict__ w_t4,
                         const float* __restrict__ w_pl4,
                         float* __restrict__ out) {
  int b = blockIdx.x;
  int z = blockIdx.y;                          // c-range [z*128, z*128+128)
  int t = threadIdx.x;
  int w = t & 15, g = t >> 4;                  // g in [0,16)
  const float* base = p5 + (size_t)b * 65536 + z * 16384;
  const float* wt = w_t4 + z * 128;
  float acc = 0.f;
  for (int j = g; j < 1024; j += 16) {         // j = c_local*8 + h
    acc += wt[j >> 3] * w_pl4[j & 7] * base[j * 16 + w];
  }
  acc += __shfl_xor(acc, 16);
  acc += __shfl_xor(acc, 32);
  if ((t & 48) == 0) atomicAdd(&out[b * 240 + 224 + w], acc);
}

// ---------------- fused conv3x3+relu+tidy+pool, R=4 rows per block ----------
// Block: 512 thr = 8 waves. Wave grid WM x WN (WN = W/16, WM = 8/WN); each
// wave: 1 N-slice (16 cols) x MT=8/WM cout-tiles x R=4 rows. 12 stages
// (4 cin-chunks x 3 kh), mfma_f32_16x16x32_bf16, one barrier per stage.
template<int H, int W, int COLBASE>
__global__ __launch_bounds__(512, 2)
void conv_fused_k(const float* __restrict__ p,
                  const unsigned short* __restrict__ wl,  // [4][3][3][4][128][8]
                  const float* __restrict__ b_s,
                  const float* __restrict__ w_t,
                  const float* __restrict__ w_pl,
                  float* __restrict__ out) {
  constexpr int R  = 4;
  constexpr int WP = W + 2;
  constexpr int HW = H * W;
  constexpr int WN = W / 16;        // waves along N
  constexpr int WM = 8 / WN;        // waves along M
  constexpr int MT = 8 / WM;        // 16-cout tiles per wave
  constexpr int SLOTS = 2 * 4 * W;  // 2 rows x 4 qg x W per stage
  constexpr int SPT = (SLOTS + 511) / 512;

  __shared__ __align__(16) unsigned short Xs[2][4][6][WP][8];      // [cbuf][qg][rowslot][pos][8c]
  __shared__ __align__(16) unsigned short Ws[2][3][4][128][8];     // [sbuf][kw][qg][cout][8c]

  const int tid  = threadIdx.x;
  const int wave = tid >> 6, lane = tid & 63;
  const int lm = lane & 15, q = lane >> 4;
  const int mw = wave / WN, ns = wave % WN;
  const int hb = blockIdx.x * R;
  const int b  = blockIdx.y;
  const float* pb = p + (size_t)b * 128 * HW;

  // ---- staging slot precompute (constant across stages) ----
  bool sok[SPT];
  int  h0k[SPT];                     // hin = h0k + 2*kh
  int  xbase[SPT];                   // LDS short-offset within a cbuf, row kh=0
  const float* sbase[SPT];
#pragma unroll
  for (int k = 0; k < SPT; ++k) {
    int slot = tid + 512 * k;
    sok[k] = (SLOTS % 512 == 0) ? true : (slot < SLOTS);
    int rk = slot / (4 * W);
    int qg = (slot / W) & 3;
    int wp = slot % W;
    h0k[k]   = hb - 1 + rk;
    xbase[k] = ((qg * 6 + rk) * WP + 1 + wp) * 8;
    sbase[k] = pb + (size_t)(qg * 8) * HW + wp;
  }

  float xf[SPT][8];
  s8v wreg[3];
  const unsigned short* wseg = wl + tid * 24;
  unsigned short* wdst = &Ws[0][0][0][0][0] + tid * 24;

  auto issueW = [&](int t) {
    const unsigned short* s = wseg + t * 12288;
#pragma unroll
    for (int j = 0; j < 3; ++j) wreg[j] = *(const s8v*)(s + j * 8);
  };
  auto writeW = [&](int buf) {
    unsigned short* d = wdst + buf * 12288;
#pragma unroll
    for (int j = 0; j < 3; ++j) *(s8v*)(d + j * 8) = wreg[j];
  };
  // rows rel {2kh-1, 2kh} of given cin chunk
  auto issueXa = [&](float (*arr)[8], int chunk, int kh) {
#pragma unroll
    for (int k = 0; k < SPT; ++k) {
      int hin = h0k[k] + 2 * kh;
      bool ok = sok[k] && ((unsigned)hin < (unsigned)H);
      if (ok) {
        const float* s = sbase[k] + (size_t)chunk * (32 * HW) + (size_t)hin * W;
#pragma unroll
        for (int i = 0; i < 8; ++i) arr[k][i] = s[(size_t)i * HW];
      } else {
#pragma unroll
        for (int i = 0; i < 8; ++i) arr[k][i] = 0.f;
      }
    }
  };
  auto writeXa = [&](float (*arr)[8], int buf, int kh) {
    unsigned short* dst = &Xs[buf][0][0][0][0] + 2 * kh * (WP * 8);
#pragma unroll
    for (int k = 0; k < SPT; ++k) {
      if (sok[k]) {
        s8v v;
#pragma unroll
        for (int i = 0; i < 8; ++i) v[i] = (short)f32_bf16_rne(arr[k][i]);
        *(s8v*)(dst + xbase[k]) = v;
      }
    }
  };

  // ---- prologue: zero halo cols (both buffers), stage chunk0 (6 rows),
  //      W batches 0 (write) and 1 (in-flight), X issue for (chunk1, kh0) ----
  if (tid < 96) {
    int t = tid;
    int pos = (t & 1) ? (WP - 1) : 0; t >>= 1;
    int sl = t % 6; t /= 6;
    int qg = t & 3; int bf = t >> 2;
    const s8v Z = {0, 0, 0, 0, 0, 0, 0, 0};
    *(s8v*)&Xs[bf][qg][sl][pos][0] = Z;
  }
  {
    float x0[SPT][8], x1[SPT][8], x2[SPT][8];
    issueW(0);
    issueXa(x0, 0, 0);
    issueXa(x1, 0, 1);
    issueXa(x2, 0, 2);
    writeW(0);
    issueW(1);
    writeXa(x0, 0, 0);
    writeXa(x1, 0, 1);
    writeXa(x2, 0, 2);
    issueXa(xf, 1, 0);
  }
  BARRIER();

  f4v acc[R][MT];
#pragma unroll
  for (int r = 0; r < R; ++r)
#pragma unroll
    for (int mt = 0; mt < MT; ++mt)
      acc[r][mt] = (f4v){0.f, 0.f, 0.f, 0.f};

  const int ncol = ns * 16 + lm;

  // ---- 12 stages ----
  for (int c = 0; c < 4; ++c) {
#pragma unroll
    for (int kh = 0; kh < 3; ++kh) {
      const int sidx = c * 3 + kh;
      // W relay: write batch sidx+1 (loaded last stage); issue batch sidx+2
      if (sidx < 11) writeW((sidx + 1) & 1);
      if (sidx < 10) issueW(sidx + 2);
      // X: write chunk c+1 rows {2kh-1,2kh} (issued last stage) into inactive
      // buffer; issue the rows the NEXT stage will write
      if (c < 3) writeXa(xf, (c + 1) & 1, kh);
      if (kh < 2) { if (c < 3) issueXa(xf, c + 1, kh + 1); }
      else        { if (c < 2) issueXa(xf, c + 2, 0); }

      // compute: af reused over R rows, bfv reused over MT cout-tiles
      const unsigned short* WsRd = &Ws[sidx & 1][0][0][0][0];
      const unsigned short* XsRd = &Xs[c & 1][0][0][0][0];
      __builtin_amdgcn_s_setprio(1);
#pragma unroll
      for (int kw = 0; kw < 3; ++kw) {
        s8v af[MT];
#pragma unroll
        for (int mt = 0; mt < MT; ++mt)
          af[mt] = *(const s8v*)(WsRd + kw * 4096 + q * 1024 +
                                 ((mw * MT + mt) * 16 + lm) * 8);
#pragma unroll
        for (int r = 0; r < R; ++r) {
          const s8v bfv = *(const s8v*)(XsRd + ((q * 6 + (kh + r)) * WP + (ncol + kw)) * 8);
#pragma unroll
          for (int mt = 0; mt < MT; ++mt)
            acc[r][mt] = __builtin_amdgcn_mfma_f32_16x16x32_bf16(af[mt], bfv, acc[r][mt], 0, 0, 0);
        }
      }
      __builtin_amdgcn_s_setprio(0);
      if (sidx < 11) BARRIER();
    }
  }

  // ---- epilogue: bias+relu+tidy, row-weighted pool sum, quad-reduce, atomic
  float stot = 0.f;
#pragma unroll
  for (int r = 0; r < R; ++r) {
    float s = 0.f;
#pragma unroll
    for (int mt = 0; mt < MT; ++mt) {
#pragma unroll
      for (int rg = 0; rg < 4; ++rg) {
        int cout = (mw * MT + mt) * 16 + q * 4 + rg;
        float v = fmaxf(acc[r][mt][rg] + b_s[cout], 0.f);
        s = fmaf(w_t[cout], v, s);
      }
    }
    stot = fmaf(w_pl[hb + r], s, stot);
  }
  stot += __shfl_xor(stot, 16);
  stot += __shfl_xor(stot, 32);
  if (lane < 16) atomicAdd(&out[b * 240 + COLBASE + ncol], stot);
}

// ============================================================================
extern "C" void kernel_launch(void* const* d_in, const int* in_sizes, int n_in,
                              void* d_out, int out_size, void* d_ws, size_t ws_size,
                              hipStream_t stream) {
  (void)in_sizes; (void)n_in; (void)out_size; (void)ws_size;
  const float* p2   = (const float*)d_in[0];
  const float* p3   = (const float*)d_in[1];
  const float* p4   = (const float*)d_in[2];
  const float* p5   = (const float*)d_in[3];
  const float* w_s1 = (const float*)d_in[4];
  const float* b_s1 = (const float*)d_in[5];
  const float* w_s2 = (const float*)d_in[6];
  const float* b_s2 = (const float*)d_in[7];
  const float* w_s3 = (const float*)d_in[8];
  const float* b_s3 = (const float*)d_in[9];
  const float* w_t1 = (const float*)d_in[10];
  const float* b_t1 = (const float*)d_in[11];
  const float* w_t2 = (const float*)d_in[12];
  const float* b_t2 = (const float*)d_in[13];
  const float* w_t3 = (const float*)d_in[14];
  const float* b_t3 = (const float*)d_in[15];
  const float* w_t4 = (const float*)d_in[16];
  const float* b_t4 = (const float*)d_in[17];
  const float* w_pl1 = (const float*)d_in[18];
  const float* b_pl1 = (const float*)d_in[19];
  const float* w_pl2 = (const float*)d_in[20];
  const float* b_pl2 = (const float*)d_in[21];
  const float* w_pl3 = (const float*)d_in[22];
  const float* b_pl3 = (const float*)d_in[23];
  const float* w_pl4 = (const float*)d_in[24];
  const float* b_pl4 = (const float*)d_in[25];

  unsigned short* wp = (unsigned short*)d_ws;   // 442368 shorts = 884736 B
  float* out = (float*)d_out;

  prep_w_k<<<dim3(1728), dim3(256), 0, stream>>>(w_s1, w_s2, w_s3, wp);
  init_out_k<<<dim3(60), dim3(256), 0, stream>>>(out, b_t1, b_t2, b_t3, b_t4,
                                                 w_pl1, b_pl1, w_pl2, b_pl2,
                                                 w_pl3, b_pl3, w_pl4, b_pl4);
  conv_fused_k<64, 128, 0><<<dim3(16, 64), dim3(512), 0, stream>>>(
      p2, wp, b_s1, w_t1, w_pl1, out);
  conv_fused_k<32, 64, 128><<<dim3(8, 64), dim3(512), 0, stream>>>(
      p3, wp + 147456, b_s2, w_t2, w_pl2, out);
  conv_fused_k<16, 32, 192><<<dim3(4, 64), dim3(512), 0, stream>>>(
      p4, wp + 294912, b_s3, w_t3, w_pl3, out);
  level4_k<<<dim3(64, 4), dim3(256), 0, stream>>>(p5, w_t4, w_pl4, out);
}

// Round 2
// 727.438 us; speedup vs baseline: 1.0098x; 1.0098x over previous
//
#include <hip/hip_runtime.h>

// ============================================================================
// ps_component round 6: R=4 rows/block, 512-thread blocks — spill fix.
// Round-5 post-mortem: __launch_bounds__(512,2) capped VGPRs at 128; the
// 128-VGPR accumulator tile spilled to scratch (WRITE_SIZE 2MB -> 271MB,
// MfmaUtil 20%). Fix: __launch_bounds__(512,1) -> 256-VGPR cap (LDS already
// forces 1 block/CU, so no occupancy change). Structure unchanged:
//  - af reused 4x (rows), bfv reused MT x (couts) -> 0.375 reads/MFMA.
//  - Xs chunk-double-buffered, Ws stage-double-buffered, 1 barrier/stage.
// ============================================================================

typedef short s8v __attribute__((ext_vector_type(8)));   // 8 x bf16 bits
typedef float f4v __attribute__((ext_vector_type(4)));

#define BARRIER() asm volatile("s_waitcnt lgkmcnt(0)\n\ts_barrier" ::: "memory")

__device__ __forceinline__ unsigned short f32_bf16_rne(float f) {
  union { float f; unsigned int u; } v;
  v.f = f;
  unsigned int u = v.u;
  u += 0x7FFFu + ((u >> 16) & 1u);
  return (unsigned short)(u >> 16);
}

// ---------------- prep W: OIHW fp32 -> [s][chunk][kh][kw][qg][cout][8c] -----
__global__ void prep_w_k(const float* __restrict__ w1,
                         const float* __restrict__ w2,
                         const float* __restrict__ w3,
                         unsigned short* __restrict__ out) {
  int idx = blockIdx.x * 256 + threadIdx.x;   // total 3*4*3*3*4*128*8 = 442368
  if (idx >= 442368) return;
  int i    = idx & 7;
  int cout = (idx >> 3) & 127;
  int t    = idx >> 10;
  int qg = t & 3; t >>= 2;
  int kw = t % 3; t /= 3;
  int kh = t % 3; t /= 3;
  int chunk = t & 3; t >>= 2;
  int s = t;
  const float* w = (s == 0) ? w1 : ((s == 1) ? w2 : w3);
  int cin = chunk * 32 + qg * 8 + i;
  out[idx] = f32_bf16_rne(w[((cout * 128 + cin) * 3 + kh) * 3 + kw]);
}

// ---------------- init: out[b,c] = b_t * sum_h w_pl[h] + b_pl ---------------
__global__ void init_out_k(float* __restrict__ out,
                           const float* bt1, const float* bt2,
                           const float* bt3, const float* bt4,
                           const float* wpl1, const float* bpl1,
                           const float* wpl2, const float* bpl2,
                           const float* wpl3, const float* bpl3,
                           const float* wpl4, const float* bpl4) {
  int idx = blockIdx.x * 256 + threadIdx.x;
  if (idx >= 64 * 240) return;
  int c = idx % 240;
  const float* wpl; const float* bpl; const float* bt; int H;
  if (c < 128)      { wpl = wpl1; bpl = bpl1; bt = bt1; H = 64; }
  else if (c < 192) { wpl = wpl2; bpl = bpl2; bt = bt2; H = 32; }
  else if (c < 224) { wpl = wpl3; bpl = bpl3; bt = bt3; H = 16; }
  else              { wpl = wpl4; bpl = bpl4; bt = bt4; H = 8;  }
  float s = 0.f;
  for (int h = 0; h < H; ++h) s += wpl[h];
  out[idx] = bt[0] * s + bpl[0];
}

// ---------------- level 4: pure linear reduction over p5 --------------------
__global__ void level4_k(const float* __restrict__ p5,
                         const float* __restrict__ w_t4,
                         const float* __restrict__ w_pl4,
                         float* __restrict__ out) {
  int b = blockIdx.x;
  int z = blockIdx.y;                          // c-range [z*128, z*128+128)
  int t = threadIdx.x;
  int w = t & 15, g = t >> 4;                  // g in [0,16)
  const float* base = p5 + (size_t)b * 65536 + z * 16384;
  const float* wt = w_t4 + z * 128;
  float acc = 0.f;
  for (int j = g; j < 1024; j += 16) {         // j = c_local*8 + h
    acc += wt[j >> 3] * w_pl4[j & 7] * base[j * 16 + w];
  }
  acc += __shfl_xor(acc, 16);
  acc += __shfl_xor(acc, 32);
  if ((t & 48) == 0) atomicAdd(&out[b * 240 + 224 + w], acc);
}

// ---------------- fused conv3x3+relu+tidy+pool, R=4 rows per block ----------
// Block: 512 thr = 8 waves. Wave grid WM x WN (WN = W/16, WM = 8/WN); each
// wave: 1 N-slice (16 cols) x MT=8/WM cout-tiles x R=4 rows. 12 stages
// (4 cin-chunks x 3 kh), mfma_f32_16x16x32_bf16, one barrier per stage.
template<int H, int W, int COLBASE>
__global__ __launch_bounds__(512, 1)   // (512,2) capped VGPR=128 -> acc spill
void conv_fused_k(const float* __restrict__ p,
                  const unsigned short* __restrict__ wl,  // [4][3][3][4][128][8]
                  const float* __restrict__ b_s,
                  const float* __restrict__ w_t,
                  const float* __restrict__ w_pl,
                  float* __restrict__ out) {
  constexpr int R  = 4;
  constexpr int WP = W + 2;
  constexpr int HW = H * W;
  constexpr int WN = W / 16;        // waves along N
  constexpr int WM = 8 / WN;        // waves along M
  constexpr int MT = 8 / WM;        // 16-cout tiles per wave
  constexpr int SLOTS = 2 * 4 * W;  // 2 rows x 4 qg x W per stage
  constexpr int SPT = (SLOTS + 511) / 512;

  __shared__ __align__(16) unsigned short Xs[2][4][6][WP][8];      // [cbuf][qg][rowslot][pos][8c]
  __shared__ __align__(16) unsigned short Ws[2][3][4][128][8];     // [sbuf][kw][qg][cout][8c]

  const int tid  = threadIdx.x;
  const int wave = tid >> 6, lane = tid & 63;
  const int lm = lane & 15, q = lane >> 4;
  const int mw = wave / WN, ns = wave % WN;
  const int hb = blockIdx.x * R;
  const int b  = blockIdx.y;
  const float* pb = p + (size_t)b * 128 * HW;

  // ---- staging slot precompute (constant across stages) ----
  bool sok[SPT];
  int  h0k[SPT];                     // hin = h0k + 2*kh
  int  xbase[SPT];                   // LDS short-offset within a cbuf, row kh=0
  const float* sbase[SPT];
#pragma unroll
  for (int k = 0; k < SPT; ++k) {
    int slot = tid + 512 * k;
    sok[k] = (SLOTS % 512 == 0) ? true : (slot < SLOTS);
    int rk = slot / (4 * W);
    int qg = (slot / W) & 3;
    int wp = slot % W;
    h0k[k]   = hb - 1 + rk;
    xbase[k] = ((qg * 6 + rk) * WP + 1 + wp) * 8;
    sbase[k] = pb + (size_t)(qg * 8) * HW + wp;
  }

  float xf[SPT][8];
  s8v wreg[3];
  const unsigned short* wseg = wl + tid * 24;
  unsigned short* wdst = &Ws[0][0][0][0][0] + tid * 24;

  auto issueW = [&](int t) {
    const unsigned short* s = wseg + t * 12288;
#pragma unroll
    for (int j = 0; j < 3; ++j) wreg[j] = *(const s8v*)(s + j * 8);
  };
  auto writeW = [&](int buf) {
    unsigned short* d = wdst + buf * 12288;
#pragma unroll
    for (int j = 0; j < 3; ++j) *(s8v*)(d + j * 8) = wreg[j];
  };
  // rows rel {2kh-1, 2kh} of given cin chunk
  auto issueXa = [&](float (*arr)[8], int chunk, int kh) {
#pragma unroll
    for (int k = 0; k < SPT; ++k) {
      int hin = h0k[k] + 2 * kh;
      bool ok = sok[k] && ((unsigned)hin < (unsigned)H);
      if (ok) {
        const float* s = sbase[k] + (size_t)chunk * (32 * HW) + (size_t)hin * W;
#pragma unroll
        for (int i = 0; i < 8; ++i) arr[k][i] = s[(size_t)i * HW];
      } else {
#pragma unroll
        for (int i = 0; i < 8; ++i) arr[k][i] = 0.f;
      }
    }
  };
  auto writeXa = [&](float (*arr)[8], int buf, int kh) {
    unsigned short* dst = &Xs[buf][0][0][0][0] + 2 * kh * (WP * 8);
#pragma unroll
    for (int k = 0; k < SPT; ++k) {
      if (sok[k]) {
        s8v v;
#pragma unroll
        for (int i = 0; i < 8; ++i) v[i] = (short)f32_bf16_rne(arr[k][i]);
        *(s8v*)(dst + xbase[k]) = v;
      }
    }
  };

  // ---- prologue: zero halo cols (both buffers), stage chunk0 (6 rows),
  //      W batches 0 (write) and 1 (in-flight), X issue for (chunk1, kh0) ----
  if (tid < 96) {
    int t = tid;
    int pos = (t & 1) ? (WP - 1) : 0; t >>= 1;
    int sl = t % 6; t /= 6;
    int qg = t & 3; int bf = t >> 2;
    const s8v Z = {0, 0, 0, 0, 0, 0, 0, 0};
    *(s8v*)&Xs[bf][qg][sl][pos][0] = Z;
  }
  {
    float x0[SPT][8], x1[SPT][8], x2[SPT][8];
    issueW(0);
    issueXa(x0, 0, 0);
    issueXa(x1, 0, 1);
    issueXa(x2, 0, 2);
    writeW(0);
    issueW(1);
    writeXa(x0, 0, 0);
    writeXa(x1, 0, 1);
    writeXa(x2, 0, 2);
    issueXa(xf, 1, 0);
  }
  BARRIER();

  f4v acc[R][MT];
#pragma unroll
  for (int r = 0; r < R; ++r)
#pragma unroll
    for (int mt = 0; mt < MT; ++mt)
      acc[r][mt] = (f4v){0.f, 0.f, 0.f, 0.f};

  const int ncol = ns * 16 + lm;

  // ---- 12 stages ----
  for (int c = 0; c < 4; ++c) {
#pragma unroll
    for (int kh = 0; kh < 3; ++kh) {
      const int sidx = c * 3 + kh;
      // W relay: write batch sidx+1 (loaded last stage); issue batch sidx+2
      if (sidx < 11) writeW((sidx + 1) & 1);
      if (sidx < 10) issueW(sidx + 2);
      // X: write chunk c+1 rows {2kh-1,2kh} (issued last stage) into inactive
      // buffer; issue the rows the NEXT stage will write
      if (c < 3) writeXa(xf, (c + 1) & 1, kh);
      if (kh < 2) { if (c < 3) issueXa(xf, c + 1, kh + 1); }
      else        { if (c < 2) issueXa(xf, c + 2, 0); }

      // compute: af reused over R rows, bfv reused over MT cout-tiles
      const unsigned short* WsRd = &Ws[sidx & 1][0][0][0][0];
      const unsigned short* XsRd = &Xs[c & 1][0][0][0][0];
      __builtin_amdgcn_s_setprio(1);
#pragma unroll
      for (int kw = 0; kw < 3; ++kw) {
        s8v af[MT];
#pragma unroll
        for (int mt = 0; mt < MT; ++mt)
          af[mt] = *(const s8v*)(WsRd + kw * 4096 + q * 1024 +
                                 ((mw * MT + mt) * 16 + lm) * 8);
#pragma unroll
        for (int r = 0; r < R; ++r) {
          const s8v bfv = *(const s8v*)(XsRd + ((q * 6 + (kh + r)) * WP + (ncol + kw)) * 8);
#pragma unroll
          for (int mt = 0; mt < MT; ++mt)
            acc[r][mt] = __builtin_amdgcn_mfma_f32_16x16x32_bf16(af[mt], bfv, acc[r][mt], 0, 0, 0);
        }
      }
      __builtin_amdgcn_s_setprio(0);
      if (sidx < 11) BARRIER();
    }
  }

  // ---- epilogue: bias+relu+tidy, row-weighted pool sum, quad-reduce, atomic
  float stot = 0.f;
#pragma unroll
  for (int r = 0; r < R; ++r) {
    float s = 0.f;
#pragma unroll
    for (int mt = 0; mt < MT; ++mt) {
#pragma unroll
      for (int rg = 0; rg < 4; ++rg) {
        int cout = (mw * MT + mt) * 16 + q * 4 + rg;
        float v = fmaxf(acc[r][mt][rg] + b_s[cout], 0.f);
        s = fmaf(w_t[cout], v, s);
      }
    }
    stot = fmaf(w_pl[hb + r], s, stot);
  }
  stot += __shfl_xor(stot, 16);
  stot += __shfl_xor(stot, 32);
  if (lane < 16) atomicAdd(&out[b * 240 + COLBASE + ncol], stot);
}

// ============================================================================
extern "C" void kernel_launch(void* const* d_in, const int* in_sizes, int n_in,
                              void* d_out, int out_size, void* d_ws, size_t ws_size,
                              hipStream_t stream) {
  (void)in_sizes; (void)n_in; (void)out_size; (void)ws_size;
  const float* p2   = (const float*)d_in[0];
  const float* p3   = (const float*)d_in[1];
  const float* p4   = (const float*)d_in[2];
  const float* p5   = (const float*)d_in[3];
  const float* w_s1 = (const float*)d_in[4];
  const float* b_s1 = (const float*)d_in[5];
  const float* w_s2 = (const float*)d_in[6];
  const float* b_s2 = (const float*)d_in[7];
  const float* w_s3 = (const float*)d_in[8];
  const float* b_s3 = (const float*)d_in[9];
  const float* w_t1 = (const float*)d_in[10];
  const float* b_t1 = (const float*)d_in[11];
  const float* w_t2 = (const float*)d_in[12];
  const float* b_t2 = (const float*)d_in[13];
  const float* w_t3 = (const float*)d_in[14];
  const float* b_t3 = (const float*)d_in[15];
  const float* w_t4 = (const float*)d_in[16];
  const float* b_t4 = (const float*)d_in[17];
  const float* w_pl1 = (const float*)d_in[18];
  const float* b_pl1 = (const float*)d_in[19];
  const float* w_pl2 = (const float*)d_in[20];
  const float* b_pl2 = (const float*)d_in[21];
  const float* w_pl3 = (const float*)d_in[22];
  const float* b_pl3 = (const float*)d_in[23];
  const float* w_pl4 = (const float*)d_in[24];
  const float* b_pl4 = (const float*)d_in[25];

  unsigned short* wp = (unsigned short*)d_ws;   // 442368 shorts = 884736 B
  float* out = (float*)d_out;

  prep_w_k<<<dim3(1728), dim3(256), 0, stream>>>(w_s1, w_s2, w_s3, wp);
  init_out_k<<<dim3(60), dim3(256), 0, stream>>>(out, b_t1, b_t2, b_t3, b_t4,
                                                 w_pl1, b_pl1, w_pl2, b_pl2,
                                                 w_pl3, b_pl3, w_pl4, b_pl4);
  conv_fused_k<64, 128, 0><<<dim3(16, 64), dim3(512), 0, stream>>>(
      p2, wp, b_s1, w_t1, w_pl1, out);
  conv_fused_k<32, 64, 128><<<dim3(8, 64), dim3(512), 0, stream>>>(
      p3, wp + 147456, b_s2, w_t2, w_pl2, out);
  conv_fused_k<16, 32, 192><<<dim3(4, 64), dim3(512), 0, stream>>>(
      p4, wp + 294912, b_s3, w_t3, w_pl3, out);
  level4_k<<<dim3(64, 4), dim3(256), 0, stream>>>(p5, w_t4, w_pl4, out);
}

// Round 3
// 646.643 us; speedup vs baseline: 1.1360x; 1.1249x over previous
//
#include <hip/hip_runtime.h>

// ============================================================================
// ps_component round 7: 256-thread blocks, 1 wave/SIMD, square-ish wave tiles.
// Round-6 post-mortem: 512-thr blocks force 2 waves/EU -> 256-reg budget split
// 128 arch + 128 acc -> spill regardless of launch_bounds. Also LDS is ONE
// pipe/CU vs 4 MFMA pipes: per-CU LDS traffic (waves x reads/wave) is the
// binding resource. Fix: 4 waves/CU with fat tiles:
//   p2: R=2, wave = 128couts x 32cols x 2rows (acc 128, reads/MFMA 0.375)
//   p3: R=4, wave = 128couts x 16cols x 4rows (acc 128, 0.375)
//   p4: R=4, wave =  64couts x 16cols x 4rows (acc 64,  0.5; 2 blocks/CU)
// 256 thr = 1 wave/SIMD -> VGPR cap 512 -> no spill possible.
// Per-CU per-stage reads: 144 (was 240 in r4, 288 in r5/6) at same MFMA/SIMD.
// ============================================================================

typedef short s8v __attribute__((ext_vector_type(8)));   // 8 x bf16 bits
typedef float f4v __attribute__((ext_vector_type(4)));

#define BARRIER() asm volatile("s_waitcnt lgkmcnt(0)\n\ts_barrier" ::: "memory")

__device__ __forceinline__ unsigned short f32_bf16_rne(float f) {
  union { float f; unsigned int u; } v;
  v.f = f;
  unsigned int u = v.u;
  u += 0x7FFFu + ((u >> 16) & 1u);
  return (unsigned short)(u >> 16);
}

// ---------------- prep W: OIHW fp32 -> [s][chunk][kh][kw][qg][cout][8c] -----
__global__ void prep_w_k(const float* __restrict__ w1,
                         const float* __restrict__ w2,
                         const float* __restrict__ w3,
                         unsigned short* __restrict__ out) {
  int idx = blockIdx.x * 256 + threadIdx.x;   // total 3*4*3*3*4*128*8 = 442368
  if (idx >= 442368) return;
  int i    = idx & 7;
  int cout = (idx >> 3) & 127;
  int t    = idx >> 10;
  int qg = t & 3; t >>= 2;
  int kw = t % 3; t /= 3;
  int kh = t % 3; t /= 3;
  int chunk = t & 3; t >>= 2;
  int s = t;
  const float* w = (s == 0) ? w1 : ((s == 1) ? w2 : w3);
  int cin = chunk * 32 + qg * 8 + i;
  out[idx] = f32_bf16_rne(w[((cout * 128 + cin) * 3 + kh) * 3 + kw]);
}

// ---------------- init: out[b,c] = b_t * sum_h w_pl[h] + b_pl ---------------
__global__ void init_out_k(float* __restrict__ out,
                           const float* bt1, const float* bt2,
                           const float* bt3, const float* bt4,
                           const float* wpl1, const float* bpl1,
                           const float* wpl2, const float* bpl2,
                           const float* wpl3, const float* bpl3,
                           const float* wpl4, const float* bpl4) {
  int idx = blockIdx.x * 256 + threadIdx.x;
  if (idx >= 64 * 240) return;
  int c = idx % 240;
  const float* wpl; const float* bpl; const float* bt; int H;
  if (c < 128)      { wpl = wpl1; bpl = bpl1; bt = bt1; H = 64; }
  else if (c < 192) { wpl = wpl2; bpl = bpl2; bt = bt2; H = 32; }
  else if (c < 224) { wpl = wpl3; bpl = bpl3; bt = bt3; H = 16; }
  else              { wpl = wpl4; bpl = bpl4; bt = bt4; H = 8;  }
  float s = 0.f;
  for (int h = 0; h < H; ++h) s += wpl[h];
  out[idx] = bt[0] * s + bpl[0];
}

// ---------------- level 4: pure linear reduction over p5 --------------------
__global__ void level4_k(const float* __restrict__ p5,
                         const float* __restrict__ w_t4,
                         const float* __restrict__ w_pl4,
                         float* __restrict__ out) {
  int b = blockIdx.x;
  int z = blockIdx.y;                          // c-range [z*128, z*128+128)
  int t = threadIdx.x;
  int w = t & 15, g = t >> 4;                  // g in [0,16)
  const float* base = p5 + (size_t)b * 65536 + z * 16384;
  const float* wt = w_t4 + z * 128;
  float acc = 0.f;
  for (int j = g; j < 1024; j += 16) {         // j = c_local*8 + h
    acc += wt[j >> 3] * w_pl4[j & 7] * base[j * 16 + w];
  }
  acc += __shfl_xor(acc, 16);
  acc += __shfl_xor(acc, 32);
  if ((t & 48) == 0) atomicAdd(&out[b * 240 + 224 + w], acc);
}

// ---------------- fused conv3x3+relu+tidy+pool --------------------------------
// Block: 256 thr = 4 waves (1 per SIMD). Wave grid WM x WN; wave owns
// MT cout-tiles x NT col-tiles x R rows. 12 stages (4 cin-chunks x 3 kh),
// mfma_f32_16x16x32_bf16, one barrier per stage. X staged in 2-row bursts
// into chunk-double-buffered Xs; Ws stage-double-buffered relay.
template<int H, int W, int COLBASE>
__global__ __launch_bounds__(256, 1)
void conv_fused_k(const float* __restrict__ p,
                  const unsigned short* __restrict__ wl,  // [4][3][3][4][128][8]
                  const float* __restrict__ b_s,
                  const float* __restrict__ w_t,
                  const float* __restrict__ w_pl,
                  float* __restrict__ out) {
  constexpr int R  = (W == 128) ? 2 : 4;   // output rows per block
  constexpr int RS = R + 2;                // input rowslots per chunk
  constexpr int NB = RS / 2;               // 2-row staging bursts per chunk
  constexpr int WP = W + 2;
  constexpr int HW = H * W;
  constexpr int WN = (W >= 64) ? 4 : 2;    // waves along N
  constexpr int WM = 4 / WN;               // waves along M
  constexpr int NT = (W / 16) / WN;        // 16-col tiles per wave
  constexpr int MT = 8 / WM;               // 16-cout tiles per wave
  constexpr int SPT = (2 * 4 * W) / 256;   // staging slots/thread per burst

  __shared__ __align__(16) unsigned short Xs[2][4][RS][WP][8];   // [cbuf][qg][slot][pos][8c]
  __shared__ __align__(16) unsigned short Ws[2][3][4][128][8];   // [sbuf][kw][qg][cout][8c]

  const int tid  = threadIdx.x;
  const int wave = tid >> 6, lane = tid & 63;
  const int lm = lane & 15, q = lane >> 4;
  const int mw = wave / WN, ns = wave % WN;
  const int hb = blockIdx.x * R;
  const int b  = blockIdx.y;
  const float* pb = p + (size_t)b * 128 * HW;

  // ---- staging slot precompute (constant across stages) ----
  int rk0[SPT]; int xb[SPT]; const float* sbase[SPT];
#pragma unroll
  for (int k = 0; k < SPT; ++k) {
    int slot = tid + 256 * k;
    int rk = slot / (4 * W);                 // 0 or 1 within burst
    int qg = (slot / W) & 3;
    int wp = slot % W;
    rk0[k] = rk;
    xb[k]  = ((qg * RS + rk) * WP + 1 + wp) * 8;
    sbase[k] = pb + (size_t)(qg * 8) * HW + wp;
  }

  float xf[SPT][8];
  s8v wreg[6];
  const unsigned short* wseg = wl + wave * 512 + lane * 8;
  unsigned short* wdst = &Ws[0][0][0][0][0] + wave * 512 + lane * 8;

  auto issueW = [&](int t) {
    const unsigned short* s = wseg + t * 12288;
#pragma unroll
    for (int j = 0; j < 6; ++j) wreg[j] = *(const s8v*)(s + j * 2048);
  };
  auto writeW = [&](int buf) {
    unsigned short* d = wdst + buf * 12288;
#pragma unroll
    for (int j = 0; j < 6; ++j) *(s8v*)(d + j * 2048) = wreg[j];
  };
  // burst j = input rowslots {2j, 2j+1} (hin = hb-1+2j+rk) of a cin chunk
  auto issueXa = [&](float (*arr)[8], int chunk, int burst) {
#pragma unroll
    for (int k = 0; k < SPT; ++k) {
      int hin = hb - 1 + 2 * burst + rk0[k];
      if ((unsigned)hin < (unsigned)H) {
        const float* s = sbase[k] + (size_t)chunk * (32 * HW) + (size_t)hin * W;
#pragma unroll
        for (int i = 0; i < 8; ++i) arr[k][i] = s[(size_t)i * HW];
      } else {
#pragma unroll
        for (int i = 0; i < 8; ++i) arr[k][i] = 0.f;
      }
    }
  };
  auto writeXa = [&](float (*arr)[8], int buf, int burst) {
    unsigned short* dst = &Xs[buf][0][0][0][0] + 2 * burst * (WP * 8);
#pragma unroll
    for (int k = 0; k < SPT; ++k) {
      s8v v;
#pragma unroll
      for (int i = 0; i < 8; ++i) v[i] = (short)f32_bf16_rne(arr[k][i]);
      *(s8v*)(dst + xb[k]) = v;
    }
  };

  // ---- prologue: zero halo cols (both bufs), stage chunk0 (all RS rows),
  //      W batches 0 (write) + 1 (in-flight), issue (chunk1, burst0) ----
  if (tid < 16 * RS) {
    int idx = tid;
    int bf  = idx / (8 * RS); int rem = idx % (8 * RS);
    int qg  = rem / (2 * RS); int r2  = rem % (2 * RS);
    int sl  = r2 >> 1;
    int pos = (r2 & 1) ? (WP - 1) : 0;
    const s8v Z = {0, 0, 0, 0, 0, 0, 0, 0};
    *(s8v*)&Xs[bf][qg][sl][pos][0] = Z;
  }
  {
    float xp[NB][SPT][8];
    issueW(0);
#pragma unroll
    for (int j = 0; j < NB; ++j) issueXa(xp[j], 0, j);
    writeW(0);
    issueW(1);
#pragma unroll
    for (int j = 0; j < NB; ++j) writeXa(xp[j], 0, j);
    issueXa(xf, 1, 0);
  }
  BARRIER();

  f4v acc[R][MT][NT];
#pragma unroll
  for (int r = 0; r < R; ++r)
#pragma unroll
    for (int mt = 0; mt < MT; ++mt)
#pragma unroll
      for (int t = 0; t < NT; ++t)
        acc[r][mt][t] = (f4v){0.f, 0.f, 0.f, 0.f};

  // ---- 12 stages ----
  for (int c = 0; c < 4; ++c) {
#pragma unroll
    for (int kh = 0; kh < 3; ++kh) {
      const int sidx = c * 3 + kh;
      // W relay: write batch sidx+1 (loaded last stage); issue batch sidx+2
      if (sidx < 11) writeW((sidx + 1) & 1);
      if (sidx < 10) issueW(sidx + 2);
      // X: write burst kh of chunk c+1 into inactive buffer; issue next burst
      if (kh < NB) { if (c < 3) writeXa(xf, (c + 1) & 1, kh); }
      if (kh + 1 < NB) { if (c < 3) issueXa(xf, c + 1, kh + 1); }
      else if (kh == 2) { if (c < 2) issueXa(xf, c + 2, 0); }

      // compute: af reused over R x NT, bfv reused over MT
      const unsigned short* WsRd = &Ws[sidx & 1][0][0][0][0];
      const unsigned short* XsRd = &Xs[c & 1][0][0][0][0];
      __builtin_amdgcn_s_setprio(1);
#pragma unroll
      for (int kw = 0; kw < 3; ++kw) {
        s8v af[MT];
#pragma unroll
        for (int mt = 0; mt < MT; ++mt)
          af[mt] = *(const s8v*)(WsRd + kw * 4096 + q * 1024 +
                                 ((mw * MT + mt) * 16 + lm) * 8);
#pragma unroll
        for (int r = 0; r < R; ++r)
#pragma unroll
          for (int t = 0; t < NT; ++t) {
            const int n = (ns * NT + t) * 16 + lm;
            const s8v bfv = *(const s8v*)(XsRd + ((q * RS + (kh + r)) * WP + (n + kw)) * 8);
#pragma unroll
            for (int mt = 0; mt < MT; ++mt)
              acc[r][mt][t] = __builtin_amdgcn_mfma_f32_16x16x32_bf16(af[mt], bfv, acc[r][mt][t], 0, 0, 0);
          }
      }
      __builtin_amdgcn_s_setprio(0);
      if (sidx < 11) BARRIER();
    }
  }

  // ---- epilogue: bias+relu+tidy, row-weighted pool, quad-reduce, atomic ----
#pragma unroll
  for (int t = 0; t < NT; ++t) {
    float stot = 0.f;
#pragma unroll
    for (int r = 0; r < R; ++r) {
      float s = 0.f;
#pragma unroll
      for (int mt = 0; mt < MT; ++mt) {
#pragma unroll
        for (int rg = 0; rg < 4; ++rg) {
          int cout = (mw * MT + mt) * 16 + q * 4 + rg;
          float v = fmaxf(acc[r][mt][t][rg] + b_s[cout], 0.f);
          s = fmaf(w_t[cout], v, s);
        }
      }
      stot = fmaf(w_pl[hb + r], s, stot);
    }
    stot += __shfl_xor(stot, 16);
    stot += __shfl_xor(stot, 32);
    if (lane < 16) atomicAdd(&out[b * 240 + COLBASE + (ns * NT + t) * 16 + lm], stot);
  }
}

// ============================================================================
extern "C" void kernel_launch(void* const* d_in, const int* in_sizes, int n_in,
                              void* d_out, int out_size, void* d_ws, size_t ws_size,
                              hipStream_t stream) {
  (void)in_sizes; (void)n_in; (void)out_size; (void)ws_size;
  const float* p2   = (const float*)d_in[0];
  const float* p3   = (const float*)d_in[1];
  const float* p4   = (const float*)d_in[2];
  const float* p5   = (const float*)d_in[3];
  const float* w_s1 = (const float*)d_in[4];
  const float* b_s1 = (const float*)d_in[5];
  const float* w_s2 = (const float*)d_in[6];
  const float* b_s2 = (const float*)d_in[7];
  const float* w_s3 = (const float*)d_in[8];
  const float* b_s3 = (const float*)d_in[9];
  const float* w_t1 = (const float*)d_in[10];
  const float* b_t1 = (const float*)d_in[11];
  const float* w_t2 = (const float*)d_in[12];
  const float* b_t2 = (const float*)d_in[13];
  const float* w_t3 = (const float*)d_in[14];
  const float* b_t3 = (const float*)d_in[15];
  const float* w_t4 = (const float*)d_in[16];
  const float* b_t4 = (const float*)d_in[17];
  const float* w_pl1 = (const float*)d_in[18];
  const float* b_pl1 = (const float*)d_in[19];
  const float* w_pl2 = (const float*)d_in[20];
  const float* b_pl2 = (const float*)d_in[21];
  const float* w_pl3 = (const float*)d_in[22];
  const float* b_pl3 = (const float*)d_in[23];
  const float* w_pl4 = (const float*)d_in[24];
  const float* b_pl4 = (const float*)d_in[25];

  unsigned short* wp = (unsigned short*)d_ws;   // 442368 shorts = 884736 B
  float* out = (float*)d_out;

  prep_w_k<<<dim3(1728), dim3(256), 0, stream>>>(w_s1, w_s2, w_s3, wp);
  init_out_k<<<dim3(60), dim3(256), 0, stream>>>(out, b_t1, b_t2, b_t3, b_t4,
                                                 w_pl1, b_pl1, w_pl2, b_pl2,
                                                 w_pl3, b_pl3, w_pl4, b_pl4);
  conv_fused_k<64, 128, 0><<<dim3(32, 64), dim3(256), 0, stream>>>(
      p2, wp, b_s1, w_t1, w_pl1, out);
  conv_fused_k<32, 64, 128><<<dim3(8, 64), dim3(256), 0, stream>>>(
      p3, wp + 147456, b_s2, w_t2, w_pl2, out);
  conv_fused_k<16, 32, 192><<<dim3(4, 64), dim3(256), 0, stream>>>(
      p4, wp + 294912, b_s3, w_t3, w_pl3, out);
  level4_k<<<dim3(64, 4), dim3(256), 0, stream>>>(p5, w_t4, w_pl4, out);
}